// Round 1
// baseline (34321.680 us; speedup 1.0000x reference)
//
#include <hip/hip_runtime.h>
#include <cmath>

// LIF_complex round 6: spike-bit broadcast.
// Key structure: g(t) = spk(t) ? 1 : g(t-1) * (1 - 1/tau_g). The decay
// factor is a per-neuron CONSTANT, so the only cross-block information per
// step is the 1-bit spike flag per neuron. Round-5 exchanged the full g
// vector (2048 tagged 8-B slots = 16 KB/step); this round exchanges 16 bits
// per block packed into ONE tagged u64 slot ({tag32|bits16}; 128 slots =
// 1 KB/step) and keeps a replicated copy of g in the dot threads' own
// registers (each thread owns exactly the 8 columns it multiplies:
// speculative decay pre-poll, then 8 cndmask on the polled bits).
// Deleted from the per-step critical path vs round 5:
//   - 16 KB/step slot fetch per block (now 1 KB block-wide, 8 waves/line)
//   - the whole LDS g staging (ds_write + barrier A + 32 KB/step ds_read,
//     which carried the 1.3e8 LDS bank conflicts)
//   - 15 of 16 publish stores (one u64 via __ballot of wave 0 lanes 0-15)
// One __syncthreads per step remains (preduce handoff to wave 0);
// preduce and vbuf/sbuf are double-buffered for the single-barrier schedule.
// Numerics are bit-identical to the round-5 passing kernel (fma decay and
// rcp(tau) are exact for tau_g=2, tau_m=4; dot/butterfly/sigmoid untouched).
// Protocol safety (proven r3/r5, unchanged): tag t is published to parity
// slot t&1 only after the block passed its step-t barrier, which certifies
// all 128 tag-(t-1) slots were observed; inductively every block finished
// loading tag t-2 from that slot before it is overwritten.

#define T_STEPS 8192
#define NN      2048
#define NBLK    128
#define NTHR    1024
#define RPB     16
#define DUMP    64
#define NSLOT   128

typedef unsigned long long u64;

__device__ __forceinline__ float stable_sigmoid(float x) {
    if (x >= 0.0f) {
        return 1.0f / (1.0f + expf(-x));
    } else {
        float e = expf(x);
        return e / (1.0f + e);
    }
}

__global__ __launch_bounds__(NTHR, 2) void lif_kernel(
    const float* __restrict__ x_in,    // [T, N]
    const float* __restrict__ w,       // [N, N]
    const float* __restrict__ v_rest,  // [N]
    const float* __restrict__ tau_m,   // [N]
    const float* __restrict__ tau_g,   // [N]
    const float* __restrict__ pre_cp,  // [1]
    const float* __restrict__ post_cp, // [1]
    const float* __restrict__ v0,      // [N]
    const float* __restrict__ g0,      // [N]
    float* __restrict__ out,           // [2, T, N]
    u64* __restrict__ slots)           // [2, NSLOT] tagged spike slots (ws)
{
    __shared__ float preduce[2][4][RPB];      // double-buffered partials
    __shared__ float vbuf[2][DUMP][RPB];      // double-buffered dump window
    __shared__ float sbuf[2][DUMP][RPB];

    const int tid = threadIdx.x;
    const int b   = blockIdx.x;
    const int wv  = tid >> 6;
    const int i   = wv & 3;            // row group (4 rows)
    const int j   = wv >> 2;           // col group (512 cols)
    const int k   = tid & 63;          // lane

    // ---- w tile into named registers: rows b*16+4i..+3, cols 512j+8k..+7
    const float* wbase = w + (size_t)(b * RPB + 4 * i) * NN + 512 * j;
    const float4* r0 = (const float4*)(wbase);
    const float4* r1 = (const float4*)(wbase + NN);
    const float4* r2 = (const float4*)(wbase + 2 * NN);
    const float4* r3 = (const float4*)(wbase + 3 * NN);
    const float4 w0a = r0[2 * k], w0b = r0[2 * k + 1];
    const float4 w1a = r1[2 * k], w1b = r1[2 * k + 1];
    const float4 w2a = r2[2 * k], w2b = r2[2 * k + 1];
    const float4 w3a = r3[2 * k], w3b = r3[2 * k + 1];

    // ---- this thread's 8 g columns live in registers for the whole run
    const int c0 = 512 * j + 8 * k;    // first owned column
    float4 ga = ((const float4*)(g0 + c0))[0];
    float4 gb = ((const float4*)(g0 + c0))[1];
    const float4 tga = ((const float4*)(tau_g + c0))[0];
    const float4 tgb = ((const float4*)(tau_g + c0))[1];
    const float4 rga = make_float4(1.0f / tga.x, 1.0f / tga.y,
                                   1.0f / tga.z, 1.0f / tga.w);
    const float4 rgb = make_float4(1.0f / tgb.x, 1.0f / tgb.y,
                                   1.0f / tgb.z, 1.0f / tgb.w);
    const int slot_i  = c0 >> 4;       // owning block of these 8 cols
    const int bitbase = c0 & 15;       // 0 or 8: bit offset in that slot

    const float pre_c  = pre_cp[0];
    const float post_c = post_cp[0];

    // ---- neuron v-state lives in wave 0, lanes 0..15
    float vr = 0.f, rtm = 0.f, v = 0.f;
    if (tid < RPB) {
        const int n = b * RPB + tid;
        vr  = v_rest[n];
        rtm = 1.0f / tau_m[n];         // exact for tau_m = 4
        v   = v0[n];
    }

    for (int t = 0; t < T_STEPS; ++t) {
        // x prefetch (consumed by wave 0 after the barrier)
        float x = 0.0f;
        if (tid < RPB) x = x_in[(size_t)t * NN + b * RPB + tid];

        if (t != 0) {
            // speculative decay: independent of the incoming spike bits,
            // issues before/under the poll. fma(-r,g,g) == g - g/tau (exact
            // for tau_g = 2).
            float4 da, db;
            da.x = fmaf(-rga.x, ga.x, ga.x); da.y = fmaf(-rga.y, ga.y, ga.y);
            da.z = fmaf(-rga.z, ga.z, ga.z); da.w = fmaf(-rga.w, ga.w, ga.w);
            db.x = fmaf(-rgb.x, gb.x, gb.x); db.y = fmaf(-rgb.y, gb.y, gb.y);
            db.z = fmaf(-rgb.z, gb.z, gb.z); db.w = fmaf(-rgb.w, gb.w, gb.w);

            // ---- acquire spikes(t-1): one 8-B tagged slot per thread
            const u64* sl = slots + (size_t)((t - 1) & 1) * NSLOT + slot_i;
            const unsigned want = (unsigned)(t - 1);
            u64 A = __hip_atomic_load(sl, __ATOMIC_RELAXED,
                                      __HIP_MEMORY_SCOPE_AGENT);
            while ((unsigned)(A >> 32) != want) {
                __builtin_amdgcn_s_sleep(1);
                A = __hip_atomic_load(sl, __ATOMIC_RELAXED,
                                      __HIP_MEMORY_SCOPE_AGENT);
            }
            const unsigned bits = (unsigned)A >> bitbase;
            ga.x = (bits &   1u) ? 1.0f : da.x;
            ga.y = (bits &   2u) ? 1.0f : da.y;
            ga.z = (bits &   4u) ? 1.0f : da.z;
            ga.w = (bits &   8u) ? 1.0f : da.w;
            gb.x = (bits &  16u) ? 1.0f : db.x;
            gb.y = (bits &  32u) ? 1.0f : db.y;
            gb.z = (bits &  64u) ? 1.0f : db.z;
            gb.w = (bits & 128u) ? 1.0f : db.w;
        }

        // ---- dot: rows 4i..4i+3 x cols 512j+8k..+7, w and g from registers
        float a0 = 0.f, a1 = 0.f, a2 = 0.f, a3 = 0.f;
#define ROWFMA(acc, wa, wb)                                       \
        acc = fmaf(wa.x, ga.x, acc); acc = fmaf(wa.y, ga.y, acc); \
        acc = fmaf(wa.z, ga.z, acc); acc = fmaf(wa.w, ga.w, acc); \
        acc = fmaf(wb.x, gb.x, acc); acc = fmaf(wb.y, gb.y, acc); \
        acc = fmaf(wb.z, gb.z, acc); acc = fmaf(wb.w, gb.w, acc);
        ROWFMA(a0, w0a, w0b)
        ROWFMA(a1, w1a, w1b)
        ROWFMA(a2, w2a, w2b)
        ROWFMA(a3, w3a, w3b)
#undef ROWFMA
        // butterfly over the 64 lanes (col reduction within the wave)
#pragma unroll
        for (int m = 1; m < 64; m <<= 1) {
            a0 += __shfl_xor(a0, m, 64);
            a1 += __shfl_xor(a1, m, 64);
            a2 += __shfl_xor(a2, m, 64);
            a3 += __shfl_xor(a3, m, 64);
        }
        if (k == 0)
            ((float4*)preduce[t & 1])[j * 4 + i] = make_float4(a0, a1, a2, a3);
        __syncthreads();  // the single per-step barrier: preduce complete,
                          // all 128 tag-(t-1) slots observed block-wide

        // ---- output dump: window closed 64 steps ago, opposite buffer
        if ((t & (DUMP - 1)) == 0 && t != 0) {
            const int bb = ((t >> 6) & 1) ^ 1;
            const int t0 = t - DUMP;
            const int s  = tid >> 4;
            const int rr = tid & 15;
            size_t o = (size_t)(t0 + s) * NN + b * RPB + rr;
            out[o] = vbuf[bb][s][rr];
            out[(size_t)T_STEPS * NN + o] = sbuf[bb][s][rr];
        }

        // ---- neuron update + spike-bit publish (wave 0, lanes 0..15)
        if (tid < RPB) {
            const float* pr = (const float*)preduce[t & 1];
            float u = (pr[tid] + pr[tid + 16]) + (pr[tid + 32] + pr[tid + 48]);
            float I = post_c * stable_sigmoid(pre_c * (u + x));
            v = v + (vr - v + I) * rtm;
            float soft = stable_sigmoid(v - 30.0f);
            bool  spk  = (v >= 30.0f);
            v = spk ? vr : v;
            vbuf[(t >> 6) & 1][t & (DUMP - 1)][tid] = v;
            sbuf[(t >> 6) & 1][t & (DUMP - 1)][tid] = soft;
            u64 bal = __ballot(spk);   // bits 0..15 = this block's spikes
            if (tid == 0) {
                u64 pk = ((u64)(unsigned)t << 32) | (bal & 0xFFFFull);
                __hip_atomic_store(slots + (size_t)(t & 1) * NSLOT + b, pk,
                                   __ATOMIC_RELAXED, __HIP_MEMORY_SCOPE_AGENT);
            }
        }
        // no trailing barrier: next preduce write goes to the other parity;
        // vbuf/sbuf writes go to the other half-buffer; slot overwrite is
        // 2 steps (2 barriers) away per the tag protocol.
    }

    // ---- final window dump
    __syncthreads();
    {
        const int bb = ((T_STEPS - DUMP) >> 6) & 1;
        const int t0 = T_STEPS - DUMP;
        const int s  = tid >> 4;
        const int rr = tid & 15;
        size_t o = (size_t)(t0 + s) * NN + b * RPB + rr;
        out[o] = vbuf[bb][s][rr];
        out[(size_t)T_STEPS * NN + o] = sbuf[bb][s][rr];
    }
}

extern "C" void kernel_launch(void* const* d_in, const int* in_sizes, int n_in,
                              void* d_out, int out_size, void* d_ws, size_t ws_size,
                              hipStream_t stream) {
    const float* x_in   = (const float*)d_in[0];
    const float* w      = (const float*)d_in[1];
    const float* v_rest = (const float*)d_in[2];
    const float* tau_m  = (const float*)d_in[3];
    const float* tau_g  = (const float*)d_in[4];
    const float* pre_c  = (const float*)d_in[5];
    const float* post_c = (const float*)d_in[6];
    const float* v0     = (const float*)d_in[7];
    const float* g0     = (const float*)d_in[8];
    float* out = (float*)d_out;

    u64* slots = (u64*)d_ws;  // [2, NSLOT]

    // tag 0xFFFFFFFF never matches any t in [0, 8192)
    hipMemsetAsync(slots, 0xFF, 2 * NSLOT * sizeof(u64), stream);

    void* args[] = {
        (void*)&x_in, (void*)&w, (void*)&v_rest, (void*)&tau_m, (void*)&tau_g,
        (void*)&pre_c, (void*)&post_c, (void*)&v0, (void*)&g0,
        (void*)&out, (void*)&slots
    };
    hipLaunchCooperativeKernel((void*)lif_kernel, dim3(NBLK), dim3(NTHR),
                               args, 0, stream);
}

// Round 2
// 21185.573 us; speedup vs baseline: 1.6200x; 1.6200x over previous
//
#include <hip/hip_runtime.h>
#include <cmath>

// LIF_complex round 7: spike-bit broadcast, fabric-friendly slot layout.
// Round 6 (spike bits, 1 KB/step exchange) REGRESSED 23.9->34.3 ms despite
// deleting the LDS g path (bank conflicts 1.3e8 -> 0 confirmed). Cause:
//  (a) false sharing -- 16 different blocks' 8 B slots packed per 128 B
//      line; agent-scope traffic is serviced at the MALL, so every publish
//      fought 15 other writers + global polling for line ownership;
//  (b) redundant polling -- 1024 threads/block hammered just 16 lines.
// Round 7 keeps round 6's register-resident g + 1-bit exchange and fixes
// the fabric behavior:
//  - each block's slot padded to its OWN 128 B line (PADU=16 u64; 32 KB ws,
//    same footprint round 5 proved safe);
//  - only waves 0-1 poll: lane k of wave w polls slot 64w+k, so each of the
//    128 lines is read exactly once per block per poll round (2 MB/round
//    machine-wide -- the rate round 5 sustained), relayed via LDS sbits[128];
//  - phase-1 sbits reads are broadcast (conflict-free); costs one extra
//    __syncthreads (back to 2/step, same as round 5).
// Tag-protocol safety (r3/r5/r6): publish tag t only after barrier 1 of
// step t, which certifies all 128 slots observed at t-1, which inductively
// certifies every block finished reading tag t-2 before it is overwritten.
// Numerics bit-identical to rounds 5/6 (fma decay + rcp(tau) exact for
// tau_g=2, tau_m=4; dot/butterfly/sigmoid untouched).

#define T_STEPS 8192
#define NN      2048
#define NBLK    128
#define NTHR    1024
#define RPB     16
#define DUMP    64
#define NSLOT   128
#define PADU    16   // u64s per slot: one 128 B line per block

typedef unsigned long long u64;

__device__ __forceinline__ float stable_sigmoid(float x) {
    if (x >= 0.0f) {
        return 1.0f / (1.0f + expf(-x));
    } else {
        float e = expf(x);
        return e / (1.0f + e);
    }
}

__global__ __launch_bounds__(NTHR, 2) void lif_kernel(
    const float* __restrict__ x_in,    // [T, N]
    const float* __restrict__ w,       // [N, N]
    const float* __restrict__ v_rest,  // [N]
    const float* __restrict__ tau_m,   // [N]
    const float* __restrict__ tau_g,   // [N]
    const float* __restrict__ pre_cp,  // [1]
    const float* __restrict__ post_cp, // [1]
    const float* __restrict__ v0,      // [N]
    const float* __restrict__ g0,      // [N]
    float* __restrict__ out,           // [2, T, N]
    u64* __restrict__ slots)           // [2, NSLOT, PADU] tagged spike slots
{
    __shared__ unsigned sbits[NSLOT];         // relayed spike bits, step t-1
    __shared__ float preduce[2][4][RPB];      // double-buffered partials
    __shared__ float vbuf[2][DUMP][RPB];      // double-buffered dump window
    __shared__ float sbuf[2][DUMP][RPB];

    const int tid = threadIdx.x;
    const int b   = blockIdx.x;
    const int wv  = tid >> 6;
    const int i   = wv & 3;            // row group (4 rows)
    const int j   = wv >> 2;           // col group (512 cols)
    const int k   = tid & 63;          // lane

    // ---- w tile into named registers: rows b*16+4i..+3, cols 512j+8k..+7
    const float* wbase = w + (size_t)(b * RPB + 4 * i) * NN + 512 * j;
    const float4* r0 = (const float4*)(wbase);
    const float4* r1 = (const float4*)(wbase + NN);
    const float4* r2 = (const float4*)(wbase + 2 * NN);
    const float4* r3 = (const float4*)(wbase + 3 * NN);
    const float4 w0a = r0[2 * k], w0b = r0[2 * k + 1];
    const float4 w1a = r1[2 * k], w1b = r1[2 * k + 1];
    const float4 w2a = r2[2 * k], w2b = r2[2 * k + 1];
    const float4 w3a = r3[2 * k], w3b = r3[2 * k + 1];

    // ---- this thread's 8 g columns live in registers for the whole run
    const int c0 = 512 * j + 8 * k;    // first owned column
    float4 ga = ((const float4*)(g0 + c0))[0];
    float4 gb = ((const float4*)(g0 + c0))[1];
    const float4 tga = ((const float4*)(tau_g + c0))[0];
    const float4 tgb = ((const float4*)(tau_g + c0))[1];
    const float4 rga = make_float4(1.0f / tga.x, 1.0f / tga.y,
                                   1.0f / tga.z, 1.0f / tga.w);
    const float4 rgb = make_float4(1.0f / tgb.x, 1.0f / tgb.y,
                                   1.0f / tgb.z, 1.0f / tgb.w);
    const int slot_i  = c0 >> 4;       // owning block of these 8 cols
    const int bitbase = c0 & 15;       // 0 or 8: bit offset in that slot

    const float pre_c  = pre_cp[0];
    const float post_c = post_cp[0];

    // ---- neuron v-state lives in wave 0, lanes 0..15
    float vr = 0.f, rtm = 0.f, v = 0.f;
    if (tid < RPB) {
        const int n = b * RPB + tid;
        vr  = v_rest[n];
        rtm = 1.0f / tau_m[n];         // exact for tau_m = 4
        v   = v0[n];
    }

    for (int t = 0; t < T_STEPS; ++t) {
        // x prefetch (consumed by wave 0 after barrier 2)
        float x = 0.0f;
        if (tid < RPB) x = x_in[(size_t)t * NN + b * RPB + tid];

        float4 da = ga, db = gb;
        if (t != 0) {
            // speculative decay: independent of the incoming spike bits.
            // fma(-r,g,g) == g - g/tau (exact for tau_g = 2).
            da.x = fmaf(-rga.x, ga.x, ga.x); da.y = fmaf(-rga.y, ga.y, ga.y);
            da.z = fmaf(-rga.z, ga.z, ga.z); da.w = fmaf(-rga.w, ga.w, ga.w);
            db.x = fmaf(-rgb.x, gb.x, gb.x); db.y = fmaf(-rgb.y, gb.y, gb.y);
            db.z = fmaf(-rgb.z, gb.z, gb.z); db.w = fmaf(-rgb.w, gb.w, gb.w);

            // ---- poll spikes(t-1): waves 0-1 only, one line per lane,
            // each of the 128 slot lines read once per block per round
            if (wv < 2) {
                const int s = (wv << 6) | k;
                const u64* sl = slots +
                    ((size_t)((t - 1) & 1) * NSLOT + s) * PADU;
                const unsigned want = (unsigned)(t - 1);
                u64 A = __hip_atomic_load(sl, __ATOMIC_RELAXED,
                                          __HIP_MEMORY_SCOPE_AGENT);
                while ((unsigned)(A >> 32) != want) {
                    __builtin_amdgcn_s_sleep(1);
                    A = __hip_atomic_load(sl, __ATOMIC_RELAXED,
                                          __HIP_MEMORY_SCOPE_AGENT);
                }
                sbits[s] = (unsigned)A;   // low 16 bits = block s's spikes
            }
        }
        __syncthreads();  // barrier 1: sbits complete; certifies all 128
                          // slots observed at tag t-1 block-wide

        if (t != 0) {
            const unsigned bits = sbits[slot_i] >> bitbase;  // broadcast read
            ga.x = (bits &   1u) ? 1.0f : da.x;
            ga.y = (bits &   2u) ? 1.0f : da.y;
            ga.z = (bits &   4u) ? 1.0f : da.z;
            ga.w = (bits &   8u) ? 1.0f : da.w;
            gb.x = (bits &  16u) ? 1.0f : db.x;
            gb.y = (bits &  32u) ? 1.0f : db.y;
            gb.z = (bits &  64u) ? 1.0f : db.z;
            gb.w = (bits & 128u) ? 1.0f : db.w;
        }

        // ---- dot: rows 4i..4i+3 x cols 512j+8k..+7, w and g from registers
        float a0 = 0.f, a1 = 0.f, a2 = 0.f, a3 = 0.f;
#define ROWFMA(acc, wa, wb)                                       \
        acc = fmaf(wa.x, ga.x, acc); acc = fmaf(wa.y, ga.y, acc); \
        acc = fmaf(wa.z, ga.z, acc); acc = fmaf(wa.w, ga.w, acc); \
        acc = fmaf(wb.x, gb.x, acc); acc = fmaf(wb.y, gb.y, acc); \
        acc = fmaf(wb.z, gb.z, acc); acc = fmaf(wb.w, gb.w, acc);
        ROWFMA(a0, w0a, w0b)
        ROWFMA(a1, w1a, w1b)
        ROWFMA(a2, w2a, w2b)
        ROWFMA(a3, w3a, w3b)
#undef ROWFMA
        // butterfly over the 64 lanes (col reduction within the wave)
#pragma unroll
        for (int m = 1; m < 64; m <<= 1) {
            a0 += __shfl_xor(a0, m, 64);
            a1 += __shfl_xor(a1, m, 64);
            a2 += __shfl_xor(a2, m, 64);
            a3 += __shfl_xor(a3, m, 64);
        }
        if (k == 0)
            ((float4*)preduce[t & 1])[j * 4 + i] = make_float4(a0, a1, a2, a3);
        __syncthreads();  // barrier 2: preduce complete

        // ---- output dump: window closed 64 steps ago, opposite buffer
        if ((t & (DUMP - 1)) == 0 && t != 0) {
            const int bb = ((t >> 6) & 1) ^ 1;
            const int t0 = t - DUMP;
            const int s  = tid >> 4;
            const int rr = tid & 15;
            size_t o = (size_t)(t0 + s) * NN + b * RPB + rr;
            out[o] = vbuf[bb][s][rr];
            out[(size_t)T_STEPS * NN + o] = sbuf[bb][s][rr];
        }

        // ---- neuron update + spike-bit publish (wave 0, lanes 0..15)
        if (tid < RPB) {
            const float* pr = (const float*)preduce[t & 1];
            float u = (pr[tid] + pr[tid + 16]) + (pr[tid + 32] + pr[tid + 48]);
            float I = post_c * stable_sigmoid(pre_c * (u + x));
            v = v + (vr - v + I) * rtm;
            float soft = stable_sigmoid(v - 30.0f);
            bool  spk  = (v >= 30.0f);
            v = spk ? vr : v;
            vbuf[(t >> 6) & 1][t & (DUMP - 1)][tid] = v;
            sbuf[(t >> 6) & 1][t & (DUMP - 1)][tid] = soft;
            u64 bal = __ballot(spk);   // bits 0..15 = this block's spikes
            if (tid == 0) {
                u64 pk = ((u64)(unsigned)t << 32) | (bal & 0xFFFFull);
                __hip_atomic_store(slots + ((size_t)(t & 1) * NSLOT + b) * PADU,
                                   pk, __ATOMIC_RELAXED,
                                   __HIP_MEMORY_SCOPE_AGENT);
            }
        }
        // no trailing barrier: next sbits write is by waves 0-1 after THEIR
        // barrier-2 arrival; preduce alternates parity; vbuf half-buffers
        // alternate every 64 steps; slot overwrite is 2 steps away.
    }

    // ---- final window dump
    __syncthreads();
    {
        const int bb = ((T_STEPS - DUMP) >> 6) & 1;
        const int t0 = T_STEPS - DUMP;
        const int s  = tid >> 4;
        const int rr = tid & 15;
        size_t o = (size_t)(t0 + s) * NN + b * RPB + rr;
        out[o] = vbuf[bb][s][rr];
        out[(size_t)T_STEPS * NN + o] = sbuf[bb][s][rr];
    }
}

extern "C" void kernel_launch(void* const* d_in, const int* in_sizes, int n_in,
                              void* d_out, int out_size, void* d_ws, size_t ws_size,
                              hipStream_t stream) {
    const float* x_in   = (const float*)d_in[0];
    const float* w      = (const float*)d_in[1];
    const float* v_rest = (const float*)d_in[2];
    const float* tau_m  = (const float*)d_in[3];
    const float* tau_g  = (const float*)d_in[4];
    const float* pre_c  = (const float*)d_in[5];
    const float* post_c = (const float*)d_in[6];
    const float* v0     = (const float*)d_in[7];
    const float* g0     = (const float*)d_in[8];
    float* out = (float*)d_out;

    u64* slots = (u64*)d_ws;  // [2, NSLOT, PADU]

    // tag 0xFFFFFFFF never matches any t in [0, 8192)
    hipMemsetAsync(slots, 0xFF, 2 * NSLOT * PADU * sizeof(u64), stream);

    void* args[] = {
        (void*)&x_in, (void*)&w, (void*)&v_rest, (void*)&tau_m, (void*)&tau_g,
        (void*)&pre_c, (void*)&post_c, (void*)&v0, (void*)&g0,
        (void*)&out, (void*)&slots
    };
    hipLaunchCooperativeKernel((void*)lif_kernel, dim3(NBLK), dim3(NTHR),
                               args, 0, stream);
}

// Round 3
// 14821.091 us; speedup vs baseline: 2.3157x; 1.4294x over previous
//
#include <hip/hip_runtime.h>
#include <cmath>

// LIF_complex round 8: DPP wave reduction (LDS-pipe-free butterfly).
// Round 7 (21.2 ms) counter audit: per-step 6200 cy with VALUBusy 9%,
// HBM 0.5%. Largest hidden term: the __shfl_xor butterfly compiles to
// ds_swizzle_b32 (LDS pipe, ~5 cy throughput) -- 24/wave x 16 waves =
// 384 LDS-pipe ops ~ 1900 cy per CU per step, all inside the bar1->bar2
// critical span (invisible in VALUBusy and in SQ_LDS_BANK_CONFLICT).
// Round 8 replaces it with the classic CDNA DPP reduction:
//   row_shr:1/2/4/8 (mask F) + row_bcast15 (mask A) + row_bcast31 (mask C),
//   row sum lands in lane 63 -- 6 VALU adds per acc, ZERO LDS-pipe ops.
// Bit-exactness: the DPP tree is the mirror-ordered binary tree over the
// same leaf pairs; every combine differs from the xor-butterfly only by
// fp-add OPERAND ORDER, and fp32 add is commutative bitwise (tree shape,
// i.e. associativity, is identical). Lane 63's value == old lane 0's value
// bit-for-bit, so the entire trajectory (spikes included) is unchanged.
// absmax must stay exactly 0.001953125 -- built-in canary.
// Also (order-only changes): publish the spike word BEFORE the soft
// sigmoid / vbuf writes (sched_barrier pins it), and move the output dump
// after the update so wave 0's publish isn't delayed on dump steps.
// Fabric protocol identical to round 7 (padded 128 B slots, waves 0-1
// relay via sbits, 2 barriers, tag overwrite-safety proof unchanged).

#define T_STEPS 8192
#define NN      2048
#define NBLK    128
#define NTHR    1024
#define RPB     16
#define DUMP    64
#define NSLOT   128
#define PADU    16   // u64s per slot: one 128 B line per block

typedef unsigned long long u64;

__device__ __forceinline__ float stable_sigmoid(float x) {
    if (x >= 0.0f) {
        return 1.0f / (1.0f + expf(-x));
    } else {
        float e = expf(x);
        return e / (1.0f + e);
    }
}

// acc += dpp_shuffled(acc); masked-out / out-of-bounds lanes add 0.0f.
// Only lane 63's final value is consumed.
#define DPP_ADD(acc, ctrl, rmask)                                         \
    acc += __int_as_float(__builtin_amdgcn_update_dpp(                    \
        0, __float_as_int(acc), ctrl, rmask, 0xF, true));

// Full 64-lane sum (bitwise == xor-butterfly result), answer in lane 63.
#define WAVE_RED(acc)            \
    DPP_ADD(acc, 0x111, 0xF)     \
    DPP_ADD(acc, 0x112, 0xF)     \
    DPP_ADD(acc, 0x114, 0xF)     \
    DPP_ADD(acc, 0x118, 0xF)     \
    DPP_ADD(acc, 0x142, 0xA)     \
    DPP_ADD(acc, 0x143, 0xC)

__global__ __launch_bounds__(NTHR, 2) void lif_kernel(
    const float* __restrict__ x_in,    // [T, N]
    const float* __restrict__ w,       // [N, N]
    const float* __restrict__ v_rest,  // [N]
    const float* __restrict__ tau_m,   // [N]
    const float* __restrict__ tau_g,   // [N]
    const float* __restrict__ pre_cp,  // [1]
    const float* __restrict__ post_cp, // [1]
    const float* __restrict__ v0,      // [N]
    const float* __restrict__ g0,      // [N]
    float* __restrict__ out,           // [2, T, N]
    u64* __restrict__ slots)           // [2, NSLOT, PADU] tagged spike slots
{
    __shared__ unsigned sbits[NSLOT];         // relayed spike bits, step t-1
    __shared__ float preduce[2][4][RPB];      // double-buffered partials
    __shared__ float vbuf[2][DUMP][RPB];      // double-buffered dump window
    __shared__ float sbuf[2][DUMP][RPB];

    const int tid = threadIdx.x;
    const int b   = blockIdx.x;
    const int wv  = tid >> 6;
    const int i   = wv & 3;            // row group (4 rows)
    const int j   = wv >> 2;           // col group (512 cols)
    const int k   = tid & 63;          // lane

    // ---- w tile into named registers: rows b*16+4i..+3, cols 512j+8k..+7
    const float* wbase = w + (size_t)(b * RPB + 4 * i) * NN + 512 * j;
    const float4* r0 = (const float4*)(wbase);
    const float4* r1 = (const float4*)(wbase + NN);
    const float4* r2 = (const float4*)(wbase + 2 * NN);
    const float4* r3 = (const float4*)(wbase + 3 * NN);
    const float4 w0a = r0[2 * k], w0b = r0[2 * k + 1];
    const float4 w1a = r1[2 * k], w1b = r1[2 * k + 1];
    const float4 w2a = r2[2 * k], w2b = r2[2 * k + 1];
    const float4 w3a = r3[2 * k], w3b = r3[2 * k + 1];

    // ---- this thread's 8 g columns live in registers for the whole run
    const int c0 = 512 * j + 8 * k;    // first owned column
    float4 ga = ((const float4*)(g0 + c0))[0];
    float4 gb = ((const float4*)(g0 + c0))[1];
    const float4 tga = ((const float4*)(tau_g + c0))[0];
    const float4 tgb = ((const float4*)(tau_g + c0))[1];
    const float4 rga = make_float4(1.0f / tga.x, 1.0f / tga.y,
                                   1.0f / tga.z, 1.0f / tga.w);
    const float4 rgb = make_float4(1.0f / tgb.x, 1.0f / tgb.y,
                                   1.0f / tgb.z, 1.0f / tgb.w);
    const int slot_i  = c0 >> 4;       // owning block of these 8 cols
    const int bitbase = c0 & 15;       // 0 or 8: bit offset in that slot

    const float pre_c  = pre_cp[0];
    const float post_c = post_cp[0];

    // ---- neuron v-state lives in wave 0, lanes 0..15
    float vr = 0.f, rtm = 0.f, v = 0.f;
    if (tid < RPB) {
        const int n = b * RPB + tid;
        vr  = v_rest[n];
        rtm = 1.0f / tau_m[n];         // exact for tau_m = 4
        v   = v0[n];
    }

    for (int t = 0; t < T_STEPS; ++t) {
        // x prefetch (consumed by wave 0 after barrier 2)
        float x = 0.0f;
        if (tid < RPB) x = x_in[(size_t)t * NN + b * RPB + tid];

        float4 da = ga, db = gb;
        if (t != 0) {
            // speculative decay: independent of the incoming spike bits.
            // fma(-r,g,g) == g - g/tau (exact for tau_g = 2).
            da.x = fmaf(-rga.x, ga.x, ga.x); da.y = fmaf(-rga.y, ga.y, ga.y);
            da.z = fmaf(-rga.z, ga.z, ga.z); da.w = fmaf(-rga.w, ga.w, ga.w);
            db.x = fmaf(-rgb.x, gb.x, gb.x); db.y = fmaf(-rgb.y, gb.y, gb.y);
            db.z = fmaf(-rgb.z, gb.z, gb.z); db.w = fmaf(-rgb.w, gb.w, gb.w);

            // ---- poll spikes(t-1): waves 0-1 only, one line per lane,
            // each of the 128 slot lines read once per block per round
            if (wv < 2) {
                const int s = (wv << 6) | k;
                const u64* sl = slots +
                    ((size_t)((t - 1) & 1) * NSLOT + s) * PADU;
                const unsigned want = (unsigned)(t - 1);
                u64 A = __hip_atomic_load(sl, __ATOMIC_RELAXED,
                                          __HIP_MEMORY_SCOPE_AGENT);
                while ((unsigned)(A >> 32) != want) {
                    __builtin_amdgcn_s_sleep(1);
                    A = __hip_atomic_load(sl, __ATOMIC_RELAXED,
                                          __HIP_MEMORY_SCOPE_AGENT);
                }
                sbits[s] = (unsigned)A;   // low 16 bits = block s's spikes
            }
        }
        __syncthreads();  // barrier 1: sbits complete; certifies all 128
                          // slots observed at tag t-1 block-wide

        if (t != 0) {
            const unsigned bits = sbits[slot_i] >> bitbase;  // broadcast read
            ga.x = (bits &   1u) ? 1.0f : da.x;
            ga.y = (bits &   2u) ? 1.0f : da.y;
            ga.z = (bits &   4u) ? 1.0f : da.z;
            ga.w = (bits &   8u) ? 1.0f : da.w;
            gb.x = (bits &  16u) ? 1.0f : db.x;
            gb.y = (bits &  32u) ? 1.0f : db.y;
            gb.z = (bits &  64u) ? 1.0f : db.z;
            gb.w = (bits & 128u) ? 1.0f : db.w;
        }

        // ---- dot: rows 4i..4i+3 x cols 512j+8k..+7, w and g from registers
        float a0 = 0.f, a1 = 0.f, a2 = 0.f, a3 = 0.f;
#define ROWFMA(acc, wa, wb)                                       \
        acc = fmaf(wa.x, ga.x, acc); acc = fmaf(wa.y, ga.y, acc); \
        acc = fmaf(wa.z, ga.z, acc); acc = fmaf(wa.w, ga.w, acc); \
        acc = fmaf(wb.x, gb.x, acc); acc = fmaf(wb.y, gb.y, acc); \
        acc = fmaf(wb.z, gb.z, acc); acc = fmaf(wb.w, gb.w, acc);
        ROWFMA(a0, w0a, w0b)
        ROWFMA(a1, w1a, w1b)
        ROWFMA(a2, w2a, w2b)
        ROWFMA(a3, w3a, w3b)
#undef ROWFMA
        // 64-lane sum via DPP (VALU pipe only; bitwise == old butterfly),
        // result in lane 63
        WAVE_RED(a0)
        WAVE_RED(a1)
        WAVE_RED(a2)
        WAVE_RED(a3)
        if (k == 63)
            ((float4*)preduce[t & 1])[j * 4 + i] = make_float4(a0, a1, a2, a3);
        __syncthreads();  // barrier 2: preduce complete

        // ---- neuron update + spike-bit publish (wave 0, lanes 0..15)
        if (tid < RPB) {
            const float* pr = (const float*)preduce[t & 1];
            float u = (pr[tid] + pr[tid + 16]) + (pr[tid + 32] + pr[tid + 48]);
            float I = post_c * stable_sigmoid(pre_c * (u + x));
            v = v + (vr - v + I) * rtm;
            bool spk = (v >= 30.0f);
            u64 bal = __ballot(spk);   // bits 0..15 = this block's spikes
            if (tid == 0) {
                u64 pk = ((u64)(unsigned)t << 32) | (bal & 0xFFFFull);
                __hip_atomic_store(slots + ((size_t)(t & 1) * NSLOT + b) * PADU,
                                   pk, __ATOMIC_RELAXED,
                                   __HIP_MEMORY_SCOPE_AGENT);
            }
            // keep the expensive soft-sigmoid/LDS writes BELOW the publish
            __builtin_amdgcn_sched_barrier(0);
            float soft = stable_sigmoid(v - 30.0f);   // pre-reset v
            v = spk ? vr : v;
            vbuf[(t >> 6) & 1][t & (DUMP - 1)][tid] = v;
            sbuf[(t >> 6) & 1][t & (DUMP - 1)][tid] = soft;
        }

        // ---- output dump (after the update so it never delays the
        // publish): window closed 64 steps ago, opposite buffer
        if ((t & (DUMP - 1)) == 0 && t != 0) {
            const int bb = ((t >> 6) & 1) ^ 1;
            const int t0 = t - DUMP;
            const int s  = tid >> 4;
            const int rr = tid & 15;
            size_t o = (size_t)(t0 + s) * NN + b * RPB + rr;
            out[o] = vbuf[bb][s][rr];
            out[(size_t)T_STEPS * NN + o] = sbuf[bb][s][rr];
        }
        // no trailing barrier: next sbits write is by waves 0-1 after THEIR
        // barrier-2 arrival; preduce alternates parity; vbuf half-buffers
        // alternate every 64 steps; slot overwrite is 2 steps away.
    }

    // ---- final window dump
    __syncthreads();
    {
        const int bb = ((T_STEPS - DUMP) >> 6) & 1;
        const int t0 = T_STEPS - DUMP;
        const int s  = tid >> 4;
        const int rr = tid & 15;
        size_t o = (size_t)(t0 + s) * NN + b * RPB + rr;
        out[o] = vbuf[bb][s][rr];
        out[(size_t)T_STEPS * NN + o] = sbuf[bb][s][rr];
    }
}

extern "C" void kernel_launch(void* const* d_in, const int* in_sizes, int n_in,
                              void* d_out, int out_size, void* d_ws, size_t ws_size,
                              hipStream_t stream) {
    const float* x_in   = (const float*)d_in[0];
    const float* w      = (const float*)d_in[1];
    const float* v_rest = (const float*)d_in[2];
    const float* tau_m  = (const float*)d_in[3];
    const float* tau_g  = (const float*)d_in[4];
    const float* pre_c  = (const float*)d_in[5];
    const float* post_c = (const float*)d_in[6];
    const float* v0     = (const float*)d_in[7];
    const float* g0     = (const float*)d_in[8];
    float* out = (float*)d_out;

    u64* slots = (u64*)d_ws;  // [2, NSLOT, PADU]

    // tag 0xFFFFFFFF never matches any t in [0, 8192)
    hipMemsetAsync(slots, 0xFF, 2 * NSLOT * PADU * sizeof(u64), stream);

    void* args[] = {
        (void*)&x_in, (void*)&w, (void*)&v_rest, (void*)&tau_m, (void*)&tau_g,
        (void*)&pre_c, (void*)&post_c, (void*)&v0, (void*)&g0,
        (void*)&out, (void*)&slots
    };
    hipLaunchCooperativeKernel((void*)lif_kernel, dim3(NBLK), dim3(NTHR),
                               args, 0, stream);
}